// Round 13
// baseline (10568.529 us; speedup 1.0000x reference)
//
#include <hip/hip_runtime.h>
#include <stdint.h>

#define STEPS 100

typedef float f2 __attribute__((ext_vector_type(2)));

// ---------------------------------------------------------------------------
// Threefry2x32 (JAX-exact, 20 rounds)
// ---------------------------------------------------------------------------
__device__ __forceinline__ uint32_t rotl32(uint32_t v, int r) {
  return (v << r) | (v >> (32 - r));
}

__device__ __forceinline__ void tf2x32(uint32_t k0, uint32_t k1,
                                       uint32_t x0, uint32_t x1,
                                       uint32_t& o0, uint32_t& o1) {
  uint32_t ks2 = k0 ^ k1 ^ 0x1BD11BDAu;
  x0 += k0; x1 += k1;
#define RND(r) { x0 += x1; x1 = rotl32(x1, (r)); x1 ^= x0; }
  RND(13) RND(15) RND(26) RND(6)
  x0 += k1;  x1 += ks2 + 1u;
  RND(17) RND(29) RND(16) RND(24)
  x0 += ks2; x1 += k0 + 2u;
  RND(13) RND(15) RND(26) RND(6)
  x0 += k0;  x1 += k1 + 3u;
  RND(17) RND(29) RND(16) RND(24)
  x0 += k1;  x1 += ks2 + 4u;
  RND(13) RND(15) RND(26) RND(6)
  x0 += ks2; x1 += k0 + 5u;
#undef RND
  o0 = x0; o1 = x1;
}

__global__ void keys_k(uint32_t* __restrict__ kb) {
  int i = threadIdx.x;
  if (i < STEPS) {
    uint32_t a, b;
    tf2x32(0u, 42u, 0u, (uint32_t)i, a, b);
    kb[2 * i] = a;
    kb[2 * i + 1] = b;
  }
}

// wT2 layout [oc][ic][28-pad]: wv loads = 7 aligned float4; the 7 rp-threads
// of one oc hit the same cachelines (broadcast).
__global__ void wt_k(const float* __restrict__ w2, float* __restrict__ wT2) {
  int i = blockIdx.x * blockDim.x + threadIdx.x;
  if (i >= 50 * 560) return;
  int oc = i / 560, r = i % 560;
  int ic = r / 28, j = r % 28;
  wT2[i] = (j < 25) ? w2[oc * 500 + ic * 25 + j] : 0.f;
}

// wf0 transpose, padded: wf0T[k*256 + n] = (n<200) ? wf0[n*2450+k] : 0
__global__ void wf0t_k(const float* __restrict__ wf0,
                       float* __restrict__ wf0T) {
  int i = blockIdx.x * blockDim.x + threadIdx.x;
  if (i >= 2450 * 256) return;
  int k = i >> 8, n = i & 255;
  wf0T[i] = (n < 200) ? wf0[n * 2450 + k] : 0.f;
}

// ---------------------------------------------------------------------------
// v19 P2 block (xx-pair packing): a0/a1[j] = columns (2j,2j+1) of rows
// r0/r1. Weight = hoisted splat ({w,w} op_sel-foldable); even-kx u-pairs
// are the natural b128 register pairs; odd-kx = 8 packs shared by both
// rows. Edge terms multiply exact +/-0 -> adding +/-0 never changes acc ->
// per-output chain (kx asc within row, r0 before r1) byte-identical to the
// scalar version.
// ---------------------------------------------------------------------------
template <int JR>
__device__ __forceinline__ void p2x(const float4& q0, const float4& q1,
                                    const float4& q2, const float4& q3,
                                    const float (&wv)[28],
                                    f2 (&a0)[7], f2 (&a1)[7]) {
  f2 E[8] = {{q0.x, q0.y}, {q0.z, q0.w}, {q1.x, q1.y}, {q1.z, q1.w},
             {q2.x, q2.y}, {q2.z, q2.w}, {q3.x, q3.y}, {q3.z, q3.w}};
  f2 O[8] = {{q0.y, q0.z}, {q0.w, q1.x}, {q1.y, q1.z}, {q1.w, q2.x},
             {q2.y, q2.z}, {q2.w, q3.x}, {q3.y, q3.z}, {q3.w, 0.f}};
  if (JR < 5) {                      // row r0, ky = JR
    f2 W;
    W = f2{wv[JR * 5 + 0], wv[JR * 5 + 0]};
#pragma unroll
    for (int j = 0; j < 7; ++j) a0[j] = __builtin_elementwise_fma(W, E[j], a0[j]);
    W = f2{wv[JR * 5 + 1], wv[JR * 5 + 1]};
#pragma unroll
    for (int j = 0; j < 7; ++j) a0[j] = __builtin_elementwise_fma(W, O[j], a0[j]);
    W = f2{wv[JR * 5 + 2], wv[JR * 5 + 2]};
#pragma unroll
    for (int j = 0; j < 7; ++j) a0[j] = __builtin_elementwise_fma(W, E[j + 1], a0[j]);
    W = f2{wv[JR * 5 + 3], wv[JR * 5 + 3]};
#pragma unroll
    for (int j = 0; j < 7; ++j) a0[j] = __builtin_elementwise_fma(W, O[j + 1], a0[j]);
    W = f2{wv[JR * 5 + 4], wv[JR * 5 + 4]};
#pragma unroll
    for (int j = 0; j < 6; ++j) a0[j] = __builtin_elementwise_fma(W, E[j + 2], a0[j]);
  }
  if (JR >= 1) {                     // row r1, ky = JR-1
    constexpr int K = (JR - 1) * 5;
    f2 W;
    W = f2{wv[K + 0], wv[K + 0]};
#pragma unroll
    for (int j = 0; j < 7; ++j) a1[j] = __builtin_elementwise_fma(W, E[j], a1[j]);
    W = f2{wv[K + 1], wv[K + 1]};
#pragma unroll
    for (int j = 0; j < 7; ++j) a1[j] = __builtin_elementwise_fma(W, O[j], a1[j]);
    W = f2{wv[K + 2], wv[K + 2]};
#pragma unroll
    for (int j = 0; j < 7; ++j) a1[j] = __builtin_elementwise_fma(W, E[j + 1], a1[j]);
    W = f2{wv[K + 3], wv[K + 3]};
#pragma unroll
    for (int j = 0; j < 7; ++j) a1[j] = __builtin_elementwise_fma(W, O[j + 1], a1[j]);
    W = f2{wv[K + 4], wv[K + 4]};
#pragma unroll
    for (int j = 0; j < 6; ++j) a1[j] = __builtin_elementwise_fma(W, E[j + 2], a1[j]);
  }
}

// ---------------------------------------------------------------------------
// PERSISTENT per-sample kernel v20b: force b128 row loads (fixed fence).
// v19: xx-packing cut the FMA issue stream but SQ_LDS_BANK_CONFLICT jumped
// 4.7e7 -> 8.13e8 — the compiler re-vectorized sp1 row loads into
// overlapping misaligned ds_read_b64s feeding the O-pairs directly. v20's
// whole-float4 "+v" tie failed to compile (tied indirect register inputs).
// v20b: fence each SCALAR component ("+v"(p0.x)... 16 floats) — simple
// single-register ties. All 16 row lanes must materialize as registers ->
// the 4 ds_read_b128 survive; pair construction becomes register movs.
// No arithmetic/order change -> bit-identical output. Else frozen from v19.
// ---------------------------------------------------------------------------
__global__ __launch_bounds__(512, 2) void step_all_k(
    const float* __restrict__ x, const float* __restrict__ w1,
    const float* __restrict__ wT2, const uint32_t* __restrict__ kb,
    uint32_t* __restrict__ sp2g) {
  __shared__ __align__(16) float  xhs_l[784];          // x/2 (signed)
  __shared__ __align__(16) float  pois_l[32 * 34];     // padded, zero halo
  __shared__ __align__(16) float  sp1_l[20 * 18 * 20]; // padded, zero halo
  __shared__ __align__(16) float  m2_l[50 * 196];      // conv2 membranes
  __shared__ float    m2s_l[2450];                     // pool2 membranes
  __shared__ float    m1s_l[20 * 196];                 // pool1 membranes
  __shared__ float    m1stash[512 * 21];               // conv1 mem tt=2,3
  __shared__ uint8_t  fb[352];                         // pool2 fire bytes

  const int b  = blockIdx.x;
  const int t  = threadIdx.x;
  // P1 mapping
  const int lq = t & 255;
  const int ohu = __builtin_amdgcn_readfirstlane(t >> 8);
  const bool act1 = lq < 196;
  const int qy = lq / 14, qx = lq % 14;
  // P2 mapping: thread = (oc, row-pair)
  const bool act2 = t < 350;
  const int oc2 = t / 7;              // 0..49
  const int rp  = t % 7;              // 0..6
  const int y0  = 2 * rp;

  for (int p = t; p < 784; p += 512) {
    xhs_l[p] = x[b * 784 + p] * 0.5f;
  }
  // zero padded buffers (halos stay zero forever; data cells rewritten
  // every step before being read)
  for (int i = t; i < 32 * 34; i += 512) pois_l[i] = 0.f;
  for (int i = t; i < 20 * 360; i += 512) sp1_l[i] = 0.f;
  for (int i = t; i < 50 * 196; i += 512) m2_l[i] = 0.f;
  for (int i = t; i < 2450; i += 512) m2s_l[i] = 0.f;
  for (int i = t; i < 20 * 196; i += 512) m1s_l[i] = 0.f;
  for (int i = t; i < 512 * 21; i += 512) m1stash[i] = 0.f;
  if (t < 352) fb[t] = 0;

  // persistent register membranes: conv1 tt=0,1 only (tt=2,3 in m1stash)
  float m1p[2][10];
#pragma unroll
  for (int i = 0; i < 10; ++i) {
    m1p[0][i] = 0.f;
    m1p[1][i] = 0.f;
  }
  __syncthreads();

  // poisson for step 0 (all threads)
  {
    uint32_t k0 = kb[0], k1 = kb[1];
    for (int p = t; p < 784; p += 512) {
      uint32_t o0, o1;
      tf2x32(k0, k1, 0u, (uint32_t)(b * 784 + p), o0, o1);
      float r = __uint_as_float(((o0 ^ o1) >> 9) | 0x3F800000u) - 1.0f;
      float v = xhs_l[p];
      pois_l[(p / 28 + 2) * 34 + (p % 28 + 2)] =
          (fabsf(v) > r) ? ((v > 0.f) ? 1.f : -1.f) : 0.f;
    }
  }
  __syncthreads();

#define LDROW(rr, d) {                                                      \
    const float2* _pr = reinterpret_cast<const float2*>(                    \
        &pois_l[(2 * qy + (rr)) * 34 + 2 * qx]);                            \
    float2 _a0 = _pr[0], _a1 = _pr[1], _a2 = _pr[2];                        \
    d[0] = _a0.x; d[1] = _a0.y; d[2] = _a1.x;                               \
    d[3] = _a1.y; d[4] = _a2.x; d[5] = _a2.y; }

// materialization fence: each row = exactly 4 ds_read_b128; all 16 lanes
// must exist as scalar registers, so the compiler cannot split/refetch as
// misaligned b64 to feed pair construction. (Scalar "+v" ties only — the
// whole-float4 tie is rejected by the backend.)
#define LD4(icv, jrv, p0, p1, p2, p3) {                                     \
    const float4* _rn = reinterpret_cast<const float4*>(                    \
        sp1_l + (icv) * 360 + (y0 + (jrv)) * 20);                           \
    p0 = _rn[0]; p1 = _rn[1]; p2 = _rn[2]; p3 = _rn[3];                     \
    asm volatile("" : "+v"(p0.x), "+v"(p0.y), "+v"(p0.z), "+v"(p0.w),      \
                      "+v"(p1.x), "+v"(p1.y), "+v"(p1.z), "+v"(p1.w),      \
                      "+v"(p2.x), "+v"(p2.y), "+v"(p2.z), "+v"(p2.w),      \
                      "+v"(p3.x), "+v"(p3.y), "+v"(p3.z), "+v"(p3.w)); }

  for (int s = 0; s < STEPS; ++s) {
    // ---- P1: conv1 (10 oc of this half) + fire + pool1 + fire ----
    if (act1) {
      float rA[6], rB[6];
      LDROW(0, rA)
      LDROW(1, rB)
      float acc[4][10];
#pragma unroll
      for (int tt = 0; tt < 4; ++tt)
#pragma unroll
        for (int i = 0; i < 10; ++i) acc[tt][i] = 0.f;
#pragma unroll
      for (int ky = 0; ky < 5; ++ky) {
        // rA = padded row 2qy+ky (rows for tt 0,1), rB = row 2qy+ky+1
#pragma unroll
        for (int kx = 0; kx < 5; ++kx) {
#pragma unroll
          for (int i = 0; i < 10; ++i) {
            float w = w1[(ohu * 10 + i) * 25 + ky * 5 + kx];
            acc[0][i] += w * rA[kx];
            acc[1][i] += w * rA[kx + 1];
            acc[2][i] += w * rB[kx];
            acc[3][i] += w * rB[kx + 1];
          }
        }
        if (ky < 4) {
#pragma unroll
          for (int j = 0; j < 6; ++j) rA[j] = rB[j];
          LDROW(ky + 2, rB)
        }
      }
#pragma unroll
      for (int i = 0; i < 10; ++i) {
        float s4[4];
        // tt = 0,1: register membranes
#pragma unroll
        for (int tt = 0; tt < 2; ++tt) {
          float m = m1p[tt][i] + acc[tt][i];
          float sp = 0.f;
          if (m > 1.0f) { sp = 1.f; m = 0.f; }
          m1p[tt][i] = m;
          s4[tt] = sp;
        }
        // tt = 2,3: LDS-stashed membranes (thread-exclusive slab)
        {
          float m = m1stash[t * 21 + i] + acc[2][i];
          float sp = 0.f;
          if (m > 1.0f) { sp = 1.f; m = 0.f; }
          m1stash[t * 21 + i] = m;
          s4[2] = sp;
        }
        {
          float m = m1stash[t * 21 + 10 + i] + acc[3][i];
          float sp = 0.f;
          if (m > 1.0f) { sp = 1.f; m = 0.f; }
          m1stash[t * 21 + 10 + i] = m;
          s4[3] = sp;
        }
        float a = 0.25f * (((s4[0] + s4[1]) + s4[2]) + s4[3]);
        int mi = (ohu * 10 + i) * 196 + lq;
        float mm = m1s_l[mi] + a;
        float spp = 0.f;
        if (mm > 0.75f) { spp = 1.f; mm = 0.f; }
        m1s_l[mi] = mm;
        sp1_l[(ohu * 10 + i) * 360 + (qy + 2) * 20 + (qx + 2)] = spp;
      }
    }
    __syncthreads();

    // ---- P2: conv2 xx-packed pipeline + fused pool2; poisson on 6,7 ----
    if (act2) {
      f2 a0[7], a1[7];
#pragma unroll
      for (int j = 0; j < 7; ++j) { a0[j] = f2{0.f, 0.f}; a1[j] = f2{0.f, 0.f}; }
      float4 A0, A1, A2, A3, B0, B1, B2, B3;
      // row prologue (ic=0 rows jr0, jr1)
      LD4(0, 0, A0, A1, A2, A3)
      LD4(0, 1, B0, B1, B2, B3)
#pragma unroll 1
      for (int ic = 0; ic < 20; ++ic) {
        const int icn = (ic < 19) ? ic + 1 : 19;
        float wv[28];
        {
          const float4* wb4 =
              reinterpret_cast<const float4*>(wT2 + oc2 * 560 + ic * 28);
#pragma unroll
          for (int j = 0; j < 7; ++j) {
            float4 q = wb4[j];
            wv[4 * j]     = q.x;
            wv[4 * j + 1] = q.y;
            wv[4 * j + 2] = q.z;
            wv[4 * j + 3] = q.w;
          }
        }
        p2x<0>(A0, A1, A2, A3, wv, a0, a1);          // jr0
        LD4(ic, 2, A0, A1, A2, A3)
        __builtin_amdgcn_sched_barrier(0);
        p2x<1>(B0, B1, B2, B3, wv, a0, a1);          // jr1
        LD4(ic, 3, B0, B1, B2, B3)
        __builtin_amdgcn_sched_barrier(0);
        p2x<2>(A0, A1, A2, A3, wv, a0, a1);          // jr2
        LD4(ic, 4, A0, A1, A2, A3)
        __builtin_amdgcn_sched_barrier(0);
        p2x<3>(B0, B1, B2, B3, wv, a0, a1);          // jr3
        LD4(ic, 5, B0, B1, B2, B3)
        __builtin_amdgcn_sched_barrier(0);
        p2x<4>(A0, A1, A2, A3, wv, a0, a1);          // jr4
        LD4(icn, 0, A0, A1, A2, A3)
        __builtin_amdgcn_sched_barrier(0);
        p2x<5>(B0, B1, B2, B3, wv, a0, a1);          // jr5
        LD4(icn, 1, B0, B1, B2, B3)
        __builtin_amdgcn_sched_barrier(0);
      }
      // fire (row y0 then y0+1, xx asc — same per-element order as before)
      float f0[14], f1[14];
#pragma unroll
      for (int j = 0; j < 7; ++j) {
        {
          int li = oc2 * 196 + y0 * 14 + 2 * j;
          float m = m2_l[li] + a0[j].x;
          float sp = 0.f;
          if (m > 1.0f) { sp = 1.f; m = 0.f; }
          m2_l[li] = m;
          f0[2 * j] = sp;
        }
        {
          int li = oc2 * 196 + y0 * 14 + 2 * j + 1;
          float m = m2_l[li] + a0[j].y;
          float sp = 0.f;
          if (m > 1.0f) { sp = 1.f; m = 0.f; }
          m2_l[li] = m;
          f0[2 * j + 1] = sp;
        }
      }
#pragma unroll
      for (int j = 0; j < 7; ++j) {
        {
          int li = oc2 * 196 + (y0 + 1) * 14 + 2 * j;
          float m = m2_l[li] + a1[j].x;
          float sp = 0.f;
          if (m > 1.0f) { sp = 1.f; m = 0.f; }
          m2_l[li] = m;
          f1[2 * j] = sp;
        }
        {
          int li = oc2 * 196 + (y0 + 1) * 14 + 2 * j + 1;
          float m = m2_l[li] + a1[j].y;
          float sp = 0.f;
          if (m > 1.0f) { sp = 1.f; m = 0.f; }
          m2_l[li] = m;
          f1[2 * j + 1] = sp;
        }
      }
      // fused pool2 + fire (this thread owns pool row yo=rp of oc2)
      uint32_t byte = 0;
#pragma unroll
      for (int xo = 0; xo < 7; ++xo) {
        float a = 0.25f * (((f0[2 * xo] + f0[2 * xo + 1]) + f1[2 * xo]) +
                           f1[2 * xo + 1]);
        int e = oc2 * 49 + rp * 7 + xo;
        float m = m2s_l[e] + a;
        uint32_t bit = 0;
        if (m > 0.75f) { bit = 1; m = 0.f; }
        m2s_l[e] = m;
        byte |= bit << xo;
      }
      fb[t] = (uint8_t)byte;
    } else if (t >= 384) {
      // poisson for step s+1 under P2's shadow (waves 6,7 idle in P2)
      if (s + 1 < STEPS) {
        uint32_t k0 = kb[2 * (s + 1)], k1 = kb[2 * (s + 1) + 1];
        for (int p = t - 384; p < 784; p += 128) {
          uint32_t o0, o1;
          tf2x32(k0, k1, 0u, (uint32_t)(b * 784 + p), o0, o1);
          float r = __uint_as_float(((o0 ^ o1) >> 9) | 0x3F800000u) - 1.0f;
          float v = xhs_l[p];
          pois_l[(p / 28 + 2) * 34 + (p % 28 + 2)] =
              (fabsf(v) > r) ? ((v > 0.f) ? 1.f : -1.f) : 0.f;
        }
      }
    }
    __syncthreads();

    // ---- word assembly: bit e of sp2 stream = fb[e/7] bit (e%7) ----
    if (t < 77) {
      int j0 = (32 * t) / 7;
      uint64_t accw = 0;
#pragma unroll
      for (int jj = 0; jj < 6; ++jj) {
        int j = j0 + jj;
        uint32_t bv = (j < 350) ? (uint32_t)fb[j] : 0u;
        accw |= (uint64_t)bv << (7 * j - 32 * t + 6);
      }
      sp2g[b * 7700 + s * 77 + t] = (uint32_t)(accw >> 6);
    }
    // no barrier: next-step P1 writes don't conflict with assembly reads
  }
#undef LDROW
#undef LD4
}

// ---------------------------------------------------------------------------
// fc0 (R14-proven): block = sample, lane = neuron; wave-uniform ctz over
// spike bits; acc += wf0T[k][n] coalesced; k ascending -> bit-identical.
// ---------------------------------------------------------------------------
__global__ __launch_bounds__(256) void fc0f_k(
    const uint32_t* __restrict__ sp2g, const float* __restrict__ wf0T,
    float* __restrict__ Tf0g) {
  __shared__ uint32_t mk[77];
  const int b = blockIdx.x;
  const int n = threadIdx.x;
  float m = 0.f, T = 0.f;
  for (int s = 0; s < STEPS; ++s) {
    __syncthreads();
    if (n < 77) mk[n] = sp2g[b * 7700 + s * 77 + n];
    __syncthreads();
    float acc = 0.f;
    for (int d = 0; d < 77; ++d) {
      uint32_t um = mk[d];
      while (um) {
        int j = __builtin_ctz(um);
        um &= um - 1;
        acc += wf0T[((d << 5) + j) * 256 + n];
      }
    }
    m += acc;
    if (m > 1.0f) { T += 1.f; m = 0.f; }
  }
  if (n < 200) Tf0g[b * 200 + n] = T;
}

// ---------------------------------------------------------------------------
// final: out[b][i] = (Tf0[b][:] . wf1[i][:]) / 1 / 100   (j ascending)
// ---------------------------------------------------------------------------
__global__ void fc1_k(const float* __restrict__ Tf0,
                      const float* __restrict__ wf1,
                      float* __restrict__ out) {
  int idx = blockIdx.x * blockDim.x + threadIdx.x;
  if (idx >= 5120) return;
  int b = idx / 10, i = idx % 10;
  float a = 0.f;
  for (int j = 0; j < 200; ++j) a += Tf0[b * 200 + j] * wf1[i * 200 + j];
  out[idx] = (a / 1.0f) / 100.0f;
}

// ---------------------------------------------------------------------------
extern "C" void kernel_launch(void* const* d_in, const int* in_sizes, int n_in,
                              void* d_out, int out_size, void* d_ws, size_t ws_size,
                              hipStream_t stream) {
  (void)in_sizes; (void)n_in; (void)out_size; (void)ws_size;
  const float* x   = (const float*)d_in[0];
  const float* w1  = (const float*)d_in[1];
  const float* w2  = (const float*)d_in[2];
  const float* wf0 = (const float*)d_in[3];
  const float* wf1 = (const float*)d_in[4];
  float* out = (float*)d_out;
  char* ws = (char*)d_ws;

  // workspace: Tf0 | wT2 | keys | wf0T | sp2 bitmask  (~18.9 MB)
  const size_t tf0_b  = 512ull * 200 * 4;
  const size_t wt_b   = 50ull * 560 * 4;   // 112000 B
  const size_t key_b  = 1024;
  const size_t wf0t_b = 2450ull * 256 * 4;
  float*    Tf0g = (float*)ws;
  float*    wT2  = (float*)(ws + tf0_b);
  uint32_t* kb   = (uint32_t*)(ws + tf0_b + wt_b);
  float*    wf0T = (float*)(ws + tf0_b + wt_b + key_b);
  uint32_t* sp2g = (uint32_t*)(ws + tf0_b + wt_b + key_b + wf0t_b);

  keys_k<<<1, 128, 0, stream>>>(kb);
  wt_k<<<110, 256, 0, stream>>>(w2, wT2);
  wf0t_k<<<2450, 256, 0, stream>>>(wf0, wf0T);
  step_all_k<<<512, 512, 0, stream>>>(x, w1, wT2, kb, sp2g);
  fc0f_k<<<512, 256, 0, stream>>>(sp2g, wf0T, Tf0g);
  fc1_k<<<20, 256, 0, stream>>>(Tf0g, wf1, out);
}

// Round 14
// 9004.254 us; speedup vs baseline: 1.1737x; 1.1737x over previous
//
#include <hip/hip_runtime.h>
#include <stdint.h>

#define STEPS 100

typedef float f2 __attribute__((ext_vector_type(2)));

// ---------------------------------------------------------------------------
// Threefry2x32 (JAX-exact, 20 rounds)
// ---------------------------------------------------------------------------
__device__ __forceinline__ uint32_t rotl32(uint32_t v, int r) {
  return (v << r) | (v >> (32 - r));
}

__device__ __forceinline__ void tf2x32(uint32_t k0, uint32_t k1,
                                       uint32_t x0, uint32_t x1,
                                       uint32_t& o0, uint32_t& o1) {
  uint32_t ks2 = k0 ^ k1 ^ 0x1BD11BDAu;
  x0 += k0; x1 += k1;
#define RND(r) { x0 += x1; x1 = rotl32(x1, (r)); x1 ^= x0; }
  RND(13) RND(15) RND(26) RND(6)
  x0 += k1;  x1 += ks2 + 1u;
  RND(17) RND(29) RND(16) RND(24)
  x0 += ks2; x1 += k0 + 2u;
  RND(13) RND(15) RND(26) RND(6)
  x0 += k0;  x1 += k1 + 3u;
  RND(17) RND(29) RND(16) RND(24)
  x0 += k1;  x1 += ks2 + 4u;
  RND(13) RND(15) RND(26) RND(6)
  x0 += ks2; x1 += k0 + 5u;
#undef RND
  o0 = x0; o1 = x1;
}

__global__ void keys_k(uint32_t* __restrict__ kb) {
  int i = threadIdx.x;
  if (i < STEPS) {
    uint32_t a, b;
    tf2x32(0u, 42u, 0u, (uint32_t)i, a, b);
    kb[2 * i] = a;
    kb[2 * i + 1] = b;
  }
}

// wT2 layout [oc][ic][28-pad]: wv loads = 7 aligned float4.
__global__ void wt_k(const float* __restrict__ w2, float* __restrict__ wT2) {
  int i = blockIdx.x * blockDim.x + threadIdx.x;
  if (i >= 50 * 560) return;
  int oc = i / 560, r = i % 560;
  int ic = r / 28, j = r % 28;
  wT2[i] = (j < 25) ? w2[oc * 500 + ic * 25 + j] : 0.f;
}

// wf0 transpose, padded: wf0T[k*256 + n] = (n<200) ? wf0[n*2450+k] : 0
__global__ void wf0t_k(const float* __restrict__ wf0,
                       float* __restrict__ wf0T) {
  int i = blockIdx.x * blockDim.x + threadIdx.x;
  if (i >= 2450 * 256) return;
  int k = i >> 8, n = i & 255;
  wf0T[i] = (n < 200) ? wf0[n * 2450 + k] : 0.f;
}

// ---------------------------------------------------------------------------
// Per-row conv block (xx-pair packing, one output row, ky = KY):
// acc[j] = columns (2j, 2j+1). Weight = hoisted splat; even-kx u-pairs are
// the natural b128 register pairs; odd-kx pairs shared. kx order inside =
// 0,1,2,3,4 ascending — identical chain to the scalar version (edge terms
// multiply exact +/-0 -> adding +/-0 never changes acc).
// Pair path calls p2s<JR>(row, a0) and p2s<JR-1>(row, a1) -> same chains
// as v19's p2x. Single-row path calls p2s<KY>(row, a0) only.
// ---------------------------------------------------------------------------
template <int KY>
__device__ __forceinline__ void p2s(const float4& q0, const float4& q1,
                                    const float4& q2, const float4& q3,
                                    const float (&wv)[28], f2 (&a)[7]) {
  f2 E[8] = {{q0.x, q0.y}, {q0.z, q0.w}, {q1.x, q1.y}, {q1.z, q1.w},
             {q2.x, q2.y}, {q2.z, q2.w}, {q3.x, q3.y}, {q3.z, q3.w}};
  f2 O[8] = {{q0.y, q0.z}, {q0.w, q1.x}, {q1.y, q1.z}, {q1.w, q2.x},
             {q2.y, q2.z}, {q2.w, q3.x}, {q3.y, q3.z}, {q3.w, 0.f}};
  constexpr int K = KY * 5;
  f2 W;
  W = f2{wv[K + 0], wv[K + 0]};
#pragma unroll
  for (int j = 0; j < 7; ++j) a[j] = __builtin_elementwise_fma(W, E[j], a[j]);
  W = f2{wv[K + 1], wv[K + 1]};
#pragma unroll
  for (int j = 0; j < 7; ++j) a[j] = __builtin_elementwise_fma(W, O[j], a[j]);
  W = f2{wv[K + 2], wv[K + 2]};
#pragma unroll
  for (int j = 0; j < 7; ++j) a[j] = __builtin_elementwise_fma(W, E[j + 1], a[j]);
  W = f2{wv[K + 3], wv[K + 3]};
#pragma unroll
  for (int j = 0; j < 7; ++j) a[j] = __builtin_elementwise_fma(W, O[j + 1], a[j]);
  W = f2{wv[K + 4], wv[K + 4]};
#pragma unroll
  for (int j = 0; j < 6; ++j) a[j] = __builtin_elementwise_fma(W, E[j + 2], a[j]);
}

// ---------------------------------------------------------------------------
// PERSISTENT per-sample kernel v21: SIMD-balance the conv2 execution.
// Model fix (R13): gfx950 has NO packed-f32 rate doubling — v_pk_fma_f32
// executes at ~4cyc/wave64 (same FLOPs as scalar). The kernel is FMA-
// EXECUTION bound, and v19's P2 (350 thr = waves 0-5) distributes 6 wave-
// costs over SIMDs as {2,2,1,1}: SIMD0/1 execute ~56K cyc of conv2 FMA vs
// 28K on SIMD2/3. v21 remap: waves 0-2 keep 28-output ROW-PAIR units
// (t<192: oc=t/7, y0=2*(t%7) — oc0-26 + oc27 rows 0-5); waves 3-7 take
// SINGLE-ROW units (half cost; t in [192,508): g=384+t-192, oc=g/14,
// y=g%14). Per-SIMD P2 exec: 1.5C,1.5C,1.5C,1C vs 2C,2C,1C,1C -> critical
// SIMD -25%. Pool fusion no longer aligns -> s2_l + v17's P3 phase return
// (3 barriers/step). Every output chain still computed by one thread in
// (ic asc, ky asc, kx asc) order -> bit-identical output.
// LDS: 3136+4352+28800+9800+39200+9800+15680+43008 = 153776 B.
// ---------------------------------------------------------------------------
__global__ __launch_bounds__(512, 2) void step_all_k(
    const float* __restrict__ x, const float* __restrict__ w1,
    const float* __restrict__ wT2, const uint32_t* __restrict__ kb,
    uint32_t* __restrict__ sp2g) {
  __shared__ __align__(16) float  xhs_l[784];          // x/2 (signed)
  __shared__ __align__(16) float  pois_l[32 * 34];     // padded, zero halo
  __shared__ __align__(16) float  sp1_l[20 * 18 * 20]; // padded, zero halo
  __shared__ int8_t  s2_l[50 * 196];                   // conv2 spikes
  __shared__ __align__(16) float  m2_l[50 * 196];      // conv2 membranes
  __shared__ float    m2s_l[2450];                     // pool2 membranes
  __shared__ float    m1s_l[20 * 196];                 // pool1 membranes
  __shared__ float    m1stash[512 * 21];               // conv1 mem tt=2,3

  const int b  = blockIdx.x;
  const int t  = threadIdx.x;
  // P1 mapping
  const int lq = t & 255;
  const int ohu = __builtin_amdgcn_readfirstlane(t >> 8);
  const bool act1 = lq < 196;
  const int qy = lq / 14, qx = lq % 14;
  // P2 mapping: waves 0-2 = row-pair units, waves 3-7 = single-row units
  const bool pair2 = t < 192;
  const bool sing2 = (t >= 192) && (t < 508);
  const int ocP = t / 7;               // pair: 0..27
  const int y0P = 2 * (t % 7);         // pair: even row base
  const int gS  = 384 + (t - 192);     // single unit id
  const int ocS = gS / 14;             // single: 27..49
  const int yS  = gS % 14;             // single row

  for (int p = t; p < 784; p += 512) {
    xhs_l[p] = x[b * 784 + p] * 0.5f;
  }
  for (int i = t; i < 32 * 34; i += 512) pois_l[i] = 0.f;
  for (int i = t; i < 20 * 360; i += 512) sp1_l[i] = 0.f;
  for (int i = t; i < 50 * 196; i += 512) m2_l[i] = 0.f;
  for (int i = t; i < 2450; i += 512) m2s_l[i] = 0.f;
  for (int i = t; i < 20 * 196; i += 512) m1s_l[i] = 0.f;
  for (int i = t; i < 512 * 21; i += 512) m1stash[i] = 0.f;

  // persistent register membranes: conv1 tt=0,1 only (tt=2,3 in m1stash)
  float m1p[2][10];
#pragma unroll
  for (int i = 0; i < 10; ++i) {
    m1p[0][i] = 0.f;
    m1p[1][i] = 0.f;
  }
  __syncthreads();

  // poisson for step 0 (all threads)
  {
    uint32_t k0 = kb[0], k1 = kb[1];
    for (int p = t; p < 784; p += 512) {
      uint32_t o0, o1;
      tf2x32(k0, k1, 0u, (uint32_t)(b * 784 + p), o0, o1);
      float r = __uint_as_float(((o0 ^ o1) >> 9) | 0x3F800000u) - 1.0f;
      float v = xhs_l[p];
      pois_l[(p / 28 + 2) * 34 + (p % 28 + 2)] =
          (fabsf(v) > r) ? ((v > 0.f) ? 1.f : -1.f) : 0.f;
    }
  }
  __syncthreads();

#define LDROW(rr, d) {                                                      \
    const float2* _pr = reinterpret_cast<const float2*>(                    \
        &pois_l[(2 * qy + (rr)) * 34 + 2 * qx]);                            \
    float2 _a0 = _pr[0], _a1 = _pr[1], _a2 = _pr[2];                        \
    d[0] = _a0.x; d[1] = _a0.y; d[2] = _a1.x;                               \
    d[3] = _a1.y; d[4] = _a2.x; d[5] = _a2.y; }

#define LD4(icv, rowv, p0, p1, p2, p3) {                                    \
    const float4* _rn = reinterpret_cast<const float4*>(                    \
        sp1_l + (icv) * 360 + (rowv) * 20);                                 \
    p0 = _rn[0]; p1 = _rn[1]; p2 = _rn[2]; p3 = _rn[3]; }

  for (int s = 0; s < STEPS; ++s) {
    // ---- P1: conv1 (10 oc of this half) + fire + pool1 + fire ----
    if (act1) {
      float rA[6], rB[6];
      LDROW(0, rA)
      LDROW(1, rB)
      float acc[4][10];
#pragma unroll
      for (int tt = 0; tt < 4; ++tt)
#pragma unroll
        for (int i = 0; i < 10; ++i) acc[tt][i] = 0.f;
#pragma unroll
      for (int ky = 0; ky < 5; ++ky) {
#pragma unroll
        for (int kx = 0; kx < 5; ++kx) {
#pragma unroll
          for (int i = 0; i < 10; ++i) {
            float w = w1[(ohu * 10 + i) * 25 + ky * 5 + kx];
            acc[0][i] += w * rA[kx];
            acc[1][i] += w * rA[kx + 1];
            acc[2][i] += w * rB[kx];
            acc[3][i] += w * rB[kx + 1];
          }
        }
        if (ky < 4) {
#pragma unroll
          for (int j = 0; j < 6; ++j) rA[j] = rB[j];
          LDROW(ky + 2, rB)
        }
      }
#pragma unroll
      for (int i = 0; i < 10; ++i) {
        float s4[4];
#pragma unroll
        for (int tt = 0; tt < 2; ++tt) {
          float m = m1p[tt][i] + acc[tt][i];
          float sp = 0.f;
          if (m > 1.0f) { sp = 1.f; m = 0.f; }
          m1p[tt][i] = m;
          s4[tt] = sp;
        }
        {
          float m = m1stash[t * 21 + i] + acc[2][i];
          float sp = 0.f;
          if (m > 1.0f) { sp = 1.f; m = 0.f; }
          m1stash[t * 21 + i] = m;
          s4[2] = sp;
        }
        {
          float m = m1stash[t * 21 + 10 + i] + acc[3][i];
          float sp = 0.f;
          if (m > 1.0f) { sp = 1.f; m = 0.f; }
          m1stash[t * 21 + 10 + i] = m;
          s4[3] = sp;
        }
        float a = 0.25f * (((s4[0] + s4[1]) + s4[2]) + s4[3]);
        int mi = (ohu * 10 + i) * 196 + lq;
        float mm = m1s_l[mi] + a;
        float spp = 0.f;
        if (mm > 0.75f) { spp = 1.f; mm = 0.f; }
        m1s_l[mi] = mm;
        sp1_l[(ohu * 10 + i) * 360 + (qy + 2) * 20 + (qx + 2)] = spp;
      }
    }
    __syncthreads();

    // ---- P2: conv2, SIMD-balanced (pairs on waves 0-2, singles 3-7) ----
    if (pair2) {
      f2 a0[7], a1[7];
#pragma unroll
      for (int j = 0; j < 7; ++j) { a0[j] = f2{0.f, 0.f}; a1[j] = f2{0.f, 0.f}; }
      float4 A0, A1, A2, A3, B0, B1, B2, B3;
      LD4(0, y0P + 0, A0, A1, A2, A3)
      LD4(0, y0P + 1, B0, B1, B2, B3)
#pragma unroll 1
      for (int ic = 0; ic < 20; ++ic) {
        const int icn = (ic < 19) ? ic + 1 : 19;
        float wv[28];
        {
          const float4* wb4 =
              reinterpret_cast<const float4*>(wT2 + ocP * 560 + ic * 28);
#pragma unroll
          for (int j = 0; j < 7; ++j) {
            float4 q = wb4[j];
            wv[4 * j]     = q.x;
            wv[4 * j + 1] = q.y;
            wv[4 * j + 2] = q.z;
            wv[4 * j + 3] = q.w;
          }
        }
        p2s<0>(A0, A1, A2, A3, wv, a0);                      // jr0
        LD4(ic, y0P + 2, A0, A1, A2, A3)
        __builtin_amdgcn_sched_barrier(0);
        p2s<1>(B0, B1, B2, B3, wv, a0);                      // jr1
        p2s<0>(B0, B1, B2, B3, wv, a1);
        LD4(ic, y0P + 3, B0, B1, B2, B3)
        __builtin_amdgcn_sched_barrier(0);
        p2s<2>(A0, A1, A2, A3, wv, a0);                      // jr2
        p2s<1>(A0, A1, A2, A3, wv, a1);
        LD4(ic, y0P + 4, A0, A1, A2, A3)
        __builtin_amdgcn_sched_barrier(0);
        p2s<3>(B0, B1, B2, B3, wv, a0);                      // jr3
        p2s<2>(B0, B1, B2, B3, wv, a1);
        LD4(ic, y0P + 5, B0, B1, B2, B3)
        __builtin_amdgcn_sched_barrier(0);
        p2s<4>(A0, A1, A2, A3, wv, a0);                      // jr4
        p2s<3>(A0, A1, A2, A3, wv, a1);
        LD4(icn, y0P + 0, A0, A1, A2, A3)
        __builtin_amdgcn_sched_barrier(0);
        p2s<4>(B0, B1, B2, B3, wv, a1);                      // jr5
        LD4(icn, y0P + 1, B0, B1, B2, B3)
        __builtin_amdgcn_sched_barrier(0);
      }
      // fire (row y0 then y0+1, xx asc)
#pragma unroll
      for (int j = 0; j < 7; ++j) {
        {
          int li = ocP * 196 + y0P * 14 + 2 * j;
          float m = m2_l[li] + a0[j].x;
          int8_t sp = 0;
          if (m > 1.0f) { sp = 1; m = 0.f; }
          m2_l[li] = m;
          s2_l[li] = sp;
        }
        {
          int li = ocP * 196 + y0P * 14 + 2 * j + 1;
          float m = m2_l[li] + a0[j].y;
          int8_t sp = 0;
          if (m > 1.0f) { sp = 1; m = 0.f; }
          m2_l[li] = m;
          s2_l[li] = sp;
        }
      }
#pragma unroll
      for (int j = 0; j < 7; ++j) {
        {
          int li = ocP * 196 + (y0P + 1) * 14 + 2 * j;
          float m = m2_l[li] + a1[j].x;
          int8_t sp = 0;
          if (m > 1.0f) { sp = 1; m = 0.f; }
          m2_l[li] = m;
          s2_l[li] = sp;
        }
        {
          int li = ocP * 196 + (y0P + 1) * 14 + 2 * j + 1;
          float m = m2_l[li] + a1[j].y;
          int8_t sp = 0;
          if (m > 1.0f) { sp = 1; m = 0.f; }
          m2_l[li] = m;
          s2_l[li] = sp;
        }
      }
    } else if (sing2) {
      f2 a0[7];
#pragma unroll
      for (int j = 0; j < 7; ++j) a0[j] = f2{0.f, 0.f};
      float4 A0, A1, A2, A3, B0, B1, B2, B3;
#pragma unroll 1
      for (int ic = 0; ic < 20; ++ic) {
        float wv[28];
        {
          const float4* wb4 =
              reinterpret_cast<const float4*>(wT2 + ocS * 560 + ic * 28);
#pragma unroll
          for (int j = 0; j < 7; ++j) {
            float4 q = wb4[j];
            wv[4 * j]     = q.x;
            wv[4 * j + 1] = q.y;
            wv[4 * j + 2] = q.z;
            wv[4 * j + 3] = q.w;
          }
        }
        LD4(ic, yS + 0, A0, A1, A2, A3)
        LD4(ic, yS + 1, B0, B1, B2, B3)
        p2s<0>(A0, A1, A2, A3, wv, a0);                      // ky0
        LD4(ic, yS + 2, A0, A1, A2, A3)
        __builtin_amdgcn_sched_barrier(0);
        p2s<1>(B0, B1, B2, B3, wv, a0);                      // ky1
        LD4(ic, yS + 3, B0, B1, B2, B3)
        __builtin_amdgcn_sched_barrier(0);
        p2s<2>(A0, A1, A2, A3, wv, a0);                      // ky2
        LD4(ic, yS + 4, A0, A1, A2, A3)
        __builtin_amdgcn_sched_barrier(0);
        p2s<3>(B0, B1, B2, B3, wv, a0);                      // ky3
        __builtin_amdgcn_sched_barrier(0);
        p2s<4>(A0, A1, A2, A3, wv, a0);                      // ky4
        __builtin_amdgcn_sched_barrier(0);
      }
      // fire (row yS, xx asc)
#pragma unroll
      for (int j = 0; j < 7; ++j) {
        {
          int li = ocS * 196 + yS * 14 + 2 * j;
          float m = m2_l[li] + a0[j].x;
          int8_t sp = 0;
          if (m > 1.0f) { sp = 1; m = 0.f; }
          m2_l[li] = m;
          s2_l[li] = sp;
        }
        {
          int li = ocS * 196 + yS * 14 + 2 * j + 1;
          float m = m2_l[li] + a0[j].y;
          int8_t sp = 0;
          if (m > 1.0f) { sp = 1; m = 0.f; }
          m2_l[li] = m;
          s2_l[li] = sp;
        }
      }
    }
    __syncthreads();

    // ---- P3: pool2 + fire -> ballot pack, + poisson(s+1) ----
#pragma unroll
    for (int i = 0; i < 5; ++i) {
      int e = i * 512 + t;
      bool fire = false;
      if (e < 2450) {
        int oc = e / 49, qq = e % 49;
        int yo = qq / 7, xo = qq % 7;
        int ib = oc * 196 + 2 * yo * 14 + 2 * xo;
        float s00 = (float)s2_l[ib];
        float s01 = (float)s2_l[ib + 1];
        float s10 = (float)s2_l[ib + 14];
        float s11 = (float)s2_l[ib + 15];
        float a = 0.25f * (((s00 + s01) + s10) + s11);
        float m = m2s_l[e] + a;
        if (m > 0.75f) { fire = true; m = 0.f; }
        m2s_l[e] = m;
      }
      unsigned long long mask = __ballot(fire);
      int base = (e & ~63);
      if ((t & 63) == 0 && base < 2450) {
        int d = base >> 5;
        sp2g[b * 7700 + s * 77 + d] = (uint32_t)mask;
        if (base + 32 < 2450)
          sp2g[b * 7700 + s * 77 + d + 1] = (uint32_t)(mask >> 32);
      }
    }
    if (s + 1 < STEPS) {
      uint32_t k0 = kb[2 * (s + 1)], k1 = kb[2 * (s + 1) + 1];
      for (int p = t; p < 784; p += 512) {
        uint32_t o0, o1;
        tf2x32(k0, k1, 0u, (uint32_t)(b * 784 + p), o0, o1);
        float r = __uint_as_float(((o0 ^ o1) >> 9) | 0x3F800000u) - 1.0f;
        float v = xhs_l[p];
        pois_l[(p / 28 + 2) * 34 + (p % 28 + 2)] =
            (fabsf(v) > r) ? ((v > 0.f) ? 1.f : -1.f) : 0.f;
      }
    }
    __syncthreads();
  }
#undef LDROW
#undef LD4
}

// ---------------------------------------------------------------------------
// fc0 (R14-proven): block = sample, lane = neuron; wave-uniform ctz over
// spike bits; acc += wf0T[k][n] coalesced; k ascending -> bit-identical.
// ---------------------------------------------------------------------------
__global__ __launch_bounds__(256) void fc0f_k(
    const uint32_t* __restrict__ sp2g, const float* __restrict__ wf0T,
    float* __restrict__ Tf0g) {
  __shared__ uint32_t mk[77];
  const int b = blockIdx.x;
  const int n = threadIdx.x;
  float m = 0.f, T = 0.f;
  for (int s = 0; s < STEPS; ++s) {
    __syncthreads();
    if (n < 77) mk[n] = sp2g[b * 7700 + s * 77 + n];
    __syncthreads();
    float acc = 0.f;
    for (int d = 0; d < 77; ++d) {
      uint32_t um = mk[d];
      while (um) {
        int j = __builtin_ctz(um);
        um &= um - 1;
        acc += wf0T[((d << 5) + j) * 256 + n];
      }
    }
    m += acc;
    if (m > 1.0f) { T += 1.f; m = 0.f; }
  }
  if (n < 200) Tf0g[b * 200 + n] = T;
}

// ---------------------------------------------------------------------------
// final: out[b][i] = (Tf0[b][:] . wf1[i][:]) / 1 / 100   (j ascending)
// ---------------------------------------------------------------------------
__global__ void fc1_k(const float* __restrict__ Tf0,
                      const float* __restrict__ wf1,
                      float* __restrict__ out) {
  int idx = blockIdx.x * blockDim.x + threadIdx.x;
  if (idx >= 5120) return;
  int b = idx / 10, i = idx % 10;
  float a = 0.f;
  for (int j = 0; j < 200; ++j) a += Tf0[b * 200 + j] * wf1[i * 200 + j];
  out[idx] = (a / 1.0f) / 100.0f;
}

// ---------------------------------------------------------------------------
extern "C" void kernel_launch(void* const* d_in, const int* in_sizes, int n_in,
                              void* d_out, int out_size, void* d_ws, size_t ws_size,
                              hipStream_t stream) {
  (void)in_sizes; (void)n_in; (void)out_size; (void)ws_size;
  const float* x   = (const float*)d_in[0];
  const float* w1  = (const float*)d_in[1];
  const float* w2  = (const float*)d_in[2];
  const float* wf0 = (const float*)d_in[3];
  const float* wf1 = (const float*)d_in[4];
  float* out = (float*)d_out;
  char* ws = (char*)d_ws;

  // workspace: Tf0 | wT2 | keys | wf0T | sp2 bitmask  (~18.9 MB)
  const size_t tf0_b  = 512ull * 200 * 4;
  const size_t wt_b   = 50ull * 560 * 4;   // 112000 B
  const size_t key_b  = 1024;
  const size_t wf0t_b = 2450ull * 256 * 4;
  float*    Tf0g = (float*)ws;
  float*    wT2  = (float*)(ws + tf0_b);
  uint32_t* kb   = (uint32_t*)(ws + tf0_b + wt_b);
  float*    wf0T = (float*)(ws + tf0_b + wt_b + key_b);
  uint32_t* sp2g = (uint32_t*)(ws + tf0_b + wt_b + key_b + wf0t_b);

  keys_k<<<1, 128, 0, stream>>>(kb);
  wt_k<<<110, 256, 0, stream>>>(w2, wT2);
  wf0t_k<<<2450, 256, 0, stream>>>(wf0, wf0T);
  step_all_k<<<512, 512, 0, stream>>>(x, w1, wT2, kb, sp2g);
  fc0f_k<<<512, 256, 0, stream>>>(sp2g, wf0T, Tf0g);
  fc1_k<<<20, 256, 0, stream>>>(Tf0g, wf1, out);
}

// Round 15
// 8628.379 us; speedup vs baseline: 1.2249x; 1.0436x over previous
//
#include <hip/hip_runtime.h>
#include <stdint.h>

#define STEPS 100

typedef float f2 __attribute__((ext_vector_type(2)));

// ---------------------------------------------------------------------------
// Threefry2x32 (JAX-exact, 20 rounds)
// ---------------------------------------------------------------------------
__device__ __forceinline__ uint32_t rotl32(uint32_t v, int r) {
  return (v << r) | (v >> (32 - r));
}

__device__ __forceinline__ void tf2x32(uint32_t k0, uint32_t k1,
                                       uint32_t x0, uint32_t x1,
                                       uint32_t& o0, uint32_t& o1) {
  uint32_t ks2 = k0 ^ k1 ^ 0x1BD11BDAu;
  x0 += k0; x1 += k1;
#define RND(r) { x0 += x1; x1 = rotl32(x1, (r)); x1 ^= x0; }
  RND(13) RND(15) RND(26) RND(6)
  x0 += k1;  x1 += ks2 + 1u;
  RND(17) RND(29) RND(16) RND(24)
  x0 += ks2; x1 += k0 + 2u;
  RND(13) RND(15) RND(26) RND(6)
  x0 += k0;  x1 += k1 + 3u;
  RND(17) RND(29) RND(16) RND(24)
  x0 += k1;  x1 += ks2 + 4u;
  RND(13) RND(15) RND(26) RND(6)
  x0 += ks2; x1 += k0 + 5u;
#undef RND
  o0 = x0; o1 = x1;
}

__global__ void keys_k(uint32_t* __restrict__ kb) {
  int i = threadIdx.x;
  if (i < STEPS) {
    uint32_t a, b;
    tf2x32(0u, 42u, 0u, (uint32_t)i, a, b);
    kb[2 * i] = a;
    kb[2 * i + 1] = b;
  }
}

// wT2 layout [oc][ic][28-pad]: wv loads = 7 aligned float4.
__global__ void wt_k(const float* __restrict__ w2, float* __restrict__ wT2) {
  int i = blockIdx.x * blockDim.x + threadIdx.x;
  if (i >= 50 * 560) return;
  int oc = i / 560, r = i % 560;
  int ic = r / 28, j = r % 28;
  wT2[i] = (j < 25) ? w2[oc * 500 + ic * 25 + j] : 0.f;
}

// wf0 transpose, padded: wf0T[k*256 + n] = (n<200) ? wf0[n*2450+k] : 0
__global__ void wf0t_k(const float* __restrict__ wf0,
                       float* __restrict__ wf0T) {
  int i = blockIdx.x * blockDim.x + threadIdx.x;
  if (i >= 2450 * 256) return;
  int k = i >> 8, n = i & 255;
  wf0T[i] = (n < 200) ? wf0[n * 2450 + k] : 0.f;
}

// ---------------------------------------------------------------------------
// Per-row conv block (xx-pair packing, one output row, ky = KY) — v21-proven.
// Edge terms multiply exact +/-0 -> adding +/-0 never changes acc; kx order
// ascending -> chain identical to the scalar version.
// ---------------------------------------------------------------------------
template <int KY>
__device__ __forceinline__ void p2s(const float4& q0, const float4& q1,
                                    const float4& q2, const float4& q3,
                                    const float (&wv)[28], f2 (&a)[7]) {
  f2 E[8] = {{q0.x, q0.y}, {q0.z, q0.w}, {q1.x, q1.y}, {q1.z, q1.w},
             {q2.x, q2.y}, {q2.z, q2.w}, {q3.x, q3.y}, {q3.z, q3.w}};
  f2 O[8] = {{q0.y, q0.z}, {q0.w, q1.x}, {q1.y, q1.z}, {q1.w, q2.x},
             {q2.y, q2.z}, {q2.w, q3.x}, {q3.y, q3.z}, {q3.w, 0.f}};
  constexpr int K = KY * 5;
  f2 W;
  W = f2{wv[K + 0], wv[K + 0]};
#pragma unroll
  for (int j = 0; j < 7; ++j) a[j] = __builtin_elementwise_fma(W, E[j], a[j]);
  W = f2{wv[K + 1], wv[K + 1]};
#pragma unroll
  for (int j = 0; j < 7; ++j) a[j] = __builtin_elementwise_fma(W, O[j], a[j]);
  W = f2{wv[K + 2], wv[K + 2]};
#pragma unroll
  for (int j = 0; j < 7; ++j) a[j] = __builtin_elementwise_fma(W, E[j + 1], a[j]);
  W = f2{wv[K + 3], wv[K + 3]};
#pragma unroll
  for (int j = 0; j < 7; ++j) a[j] = __builtin_elementwise_fma(W, O[j + 1], a[j]);
  W = f2{wv[K + 4], wv[K + 4]};
#pragma unroll
  for (int j = 0; j < 6; ++j) a[j] = __builtin_elementwise_fma(W, E[j + 2], a[j]);
}

// ---------------------------------------------------------------------------
// PERSISTENT per-sample kernel v23: v21's SIMD-balanced conv2 + v18's fused
// pool2 extended to the mixed mapping. Wall audit at v21: 103K cyc/step,
// ~74K busy (exec-bound), ~29K idle (barrier/phase). Address the phase
// overhead: P3's pool pass (s2_l byte roundtrip + ballot) + one barrier.
//  * pairs (t<192): thread owns pool row yo=t%7 of ocP -> in-register pool
//    (v18 code path), fb[t].
//  * singles: pool rows (2yo,2yo+1) = threads g,g+1 = ADJACENT LANES (g
//    parity==lane parity; wave boundaries at even g). Pack 14 fire bits,
//    one __shfl_down(,1); even lanes reconstruct partner spikes exactly
//    (spikes in {0,1} -> bit-exact), pool, own m2s chain, fb[ocS*7+yo].
//  * poisson(s+1) = short tail of the P2 phase (all threads); P3 collapses
//    to the 77-thread word assembly; 2 barriers/step; s2_l deleted.
// Per-element m2s chains, fire order, sp2g layout unchanged -> bit-identical.
// LDS: 3136+4352+28800+39200+9800+15680+43008+352 = 144328 B.
// ---------------------------------------------------------------------------
__global__ __launch_bounds__(512, 2) void step_all_k(
    const float* __restrict__ x, const float* __restrict__ w1,
    const float* __restrict__ wT2, const uint32_t* __restrict__ kb,
    uint32_t* __restrict__ sp2g) {
  __shared__ __align__(16) float  xhs_l[784];          // x/2 (signed)
  __shared__ __align__(16) float  pois_l[32 * 34];     // padded, zero halo
  __shared__ __align__(16) float  sp1_l[20 * 18 * 20]; // padded, zero halo
  __shared__ __align__(16) float  m2_l[50 * 196];      // conv2 membranes
  __shared__ float    m2s_l[2450];                     // pool2 membranes
  __shared__ float    m1s_l[20 * 196];                 // pool1 membranes
  __shared__ float    m1stash[512 * 21];               // conv1 mem tt=2,3
  __shared__ uint8_t  fb[352];                         // pool2 fire bytes

  const int b  = blockIdx.x;
  const int t  = threadIdx.x;
  // P1 mapping
  const int lq = t & 255;
  const int ohu = __builtin_amdgcn_readfirstlane(t >> 8);
  const bool act1 = lq < 196;
  const int qy = lq / 14, qx = lq % 14;
  // P2 mapping: waves 0-2 = row-pair units, waves 3-7 = single-row units
  const bool pair2 = t < 192;
  const bool sing2 = (t >= 192) && (t < 508);
  const int ocP = t / 7;               // pair: 0..27
  const int y0P = 2 * (t % 7);         // pair: even row base
  const int gS  = 192 + t;             // single unit id (= 384 + (t-192))
  const int ocS = gS / 14;             // single: 27..49
  const int yS  = gS % 14;             // single row

  for (int p = t; p < 784; p += 512) {
    xhs_l[p] = x[b * 784 + p] * 0.5f;
  }
  for (int i = t; i < 32 * 34; i += 512) pois_l[i] = 0.f;
  for (int i = t; i < 20 * 360; i += 512) sp1_l[i] = 0.f;
  for (int i = t; i < 50 * 196; i += 512) m2_l[i] = 0.f;
  for (int i = t; i < 2450; i += 512) m2s_l[i] = 0.f;
  for (int i = t; i < 20 * 196; i += 512) m1s_l[i] = 0.f;
  for (int i = t; i < 512 * 21; i += 512) m1stash[i] = 0.f;
  if (t < 352) fb[t] = 0;

  // persistent register membranes: conv1 tt=0,1 only (tt=2,3 in m1stash)
  float m1p[2][10];
#pragma unroll
  for (int i = 0; i < 10; ++i) {
    m1p[0][i] = 0.f;
    m1p[1][i] = 0.f;
  }
  __syncthreads();

  // poisson for step 0 (all threads)
  {
    uint32_t k0 = kb[0], k1 = kb[1];
    for (int p = t; p < 784; p += 512) {
      uint32_t o0, o1;
      tf2x32(k0, k1, 0u, (uint32_t)(b * 784 + p), o0, o1);
      float r = __uint_as_float(((o0 ^ o1) >> 9) | 0x3F800000u) - 1.0f;
      float v = xhs_l[p];
      pois_l[(p / 28 + 2) * 34 + (p % 28 + 2)] =
          (fabsf(v) > r) ? ((v > 0.f) ? 1.f : -1.f) : 0.f;
    }
  }
  __syncthreads();

#define LDROW(rr, d) {                                                      \
    const float2* _pr = reinterpret_cast<const float2*>(                    \
        &pois_l[(2 * qy + (rr)) * 34 + 2 * qx]);                            \
    float2 _a0 = _pr[0], _a1 = _pr[1], _a2 = _pr[2];                        \
    d[0] = _a0.x; d[1] = _a0.y; d[2] = _a1.x;                               \
    d[3] = _a1.y; d[4] = _a2.x; d[5] = _a2.y; }

#define LD4(icv, rowv, p0, p1, p2, p3) {                                    \
    const float4* _rn = reinterpret_cast<const float4*>(                    \
        sp1_l + (icv) * 360 + (rowv) * 20);                                 \
    p0 = _rn[0]; p1 = _rn[1]; p2 = _rn[2]; p3 = _rn[3]; }

  for (int s = 0; s < STEPS; ++s) {
    // ---- P1: conv1 (10 oc of this half) + fire + pool1 + fire ----
    if (act1) {
      float rA[6], rB[6];
      LDROW(0, rA)
      LDROW(1, rB)
      float acc[4][10];
#pragma unroll
      for (int tt = 0; tt < 4; ++tt)
#pragma unroll
        for (int i = 0; i < 10; ++i) acc[tt][i] = 0.f;
#pragma unroll
      for (int ky = 0; ky < 5; ++ky) {
#pragma unroll
        for (int kx = 0; kx < 5; ++kx) {
#pragma unroll
          for (int i = 0; i < 10; ++i) {
            float w = w1[(ohu * 10 + i) * 25 + ky * 5 + kx];
            acc[0][i] += w * rA[kx];
            acc[1][i] += w * rA[kx + 1];
            acc[2][i] += w * rB[kx];
            acc[3][i] += w * rB[kx + 1];
          }
        }
        if (ky < 4) {
#pragma unroll
          for (int j = 0; j < 6; ++j) rA[j] = rB[j];
          LDROW(ky + 2, rB)
        }
      }
#pragma unroll
      for (int i = 0; i < 10; ++i) {
        float s4[4];
#pragma unroll
        for (int tt = 0; tt < 2; ++tt) {
          float m = m1p[tt][i] + acc[tt][i];
          float sp = 0.f;
          if (m > 1.0f) { sp = 1.f; m = 0.f; }
          m1p[tt][i] = m;
          s4[tt] = sp;
        }
        {
          float m = m1stash[t * 21 + i] + acc[2][i];
          float sp = 0.f;
          if (m > 1.0f) { sp = 1.f; m = 0.f; }
          m1stash[t * 21 + i] = m;
          s4[2] = sp;
        }
        {
          float m = m1stash[t * 21 + 10 + i] + acc[3][i];
          float sp = 0.f;
          if (m > 1.0f) { sp = 1.f; m = 0.f; }
          m1stash[t * 21 + 10 + i] = m;
          s4[3] = sp;
        }
        float a = 0.25f * (((s4[0] + s4[1]) + s4[2]) + s4[3]);
        int mi = (ohu * 10 + i) * 196 + lq;
        float mm = m1s_l[mi] + a;
        float spp = 0.f;
        if (mm > 0.75f) { spp = 1.f; mm = 0.f; }
        m1s_l[mi] = mm;
        sp1_l[(ohu * 10 + i) * 360 + (qy + 2) * 20 + (qx + 2)] = spp;
      }
    }
    __syncthreads();

    // ---- P2: conv2 (SIMD-balanced) + fire + FUSED pool2 -> fb ----
    if (pair2) {
      f2 a0[7], a1[7];
#pragma unroll
      for (int j = 0; j < 7; ++j) { a0[j] = f2{0.f, 0.f}; a1[j] = f2{0.f, 0.f}; }
      float4 A0, A1, A2, A3, B0, B1, B2, B3;
      LD4(0, y0P + 0, A0, A1, A2, A3)
      LD4(0, y0P + 1, B0, B1, B2, B3)
#pragma unroll 1
      for (int ic = 0; ic < 20; ++ic) {
        const int icn = (ic < 19) ? ic + 1 : 19;
        float wv[28];
        {
          const float4* wb4 =
              reinterpret_cast<const float4*>(wT2 + ocP * 560 + ic * 28);
#pragma unroll
          for (int j = 0; j < 7; ++j) {
            float4 q = wb4[j];
            wv[4 * j]     = q.x;
            wv[4 * j + 1] = q.y;
            wv[4 * j + 2] = q.z;
            wv[4 * j + 3] = q.w;
          }
        }
        p2s<0>(A0, A1, A2, A3, wv, a0);                      // jr0
        LD4(ic, y0P + 2, A0, A1, A2, A3)
        __builtin_amdgcn_sched_barrier(0);
        p2s<1>(B0, B1, B2, B3, wv, a0);                      // jr1
        p2s<0>(B0, B1, B2, B3, wv, a1);
        LD4(ic, y0P + 3, B0, B1, B2, B3)
        __builtin_amdgcn_sched_barrier(0);
        p2s<2>(A0, A1, A2, A3, wv, a0);                      // jr2
        p2s<1>(A0, A1, A2, A3, wv, a1);
        LD4(ic, y0P + 4, A0, A1, A2, A3)
        __builtin_amdgcn_sched_barrier(0);
        p2s<3>(B0, B1, B2, B3, wv, a0);                      // jr3
        p2s<2>(B0, B1, B2, B3, wv, a1);
        LD4(ic, y0P + 5, B0, B1, B2, B3)
        __builtin_amdgcn_sched_barrier(0);
        p2s<4>(A0, A1, A2, A3, wv, a0);                      // jr4
        p2s<3>(A0, A1, A2, A3, wv, a1);
        LD4(icn, y0P + 0, A0, A1, A2, A3)
        __builtin_amdgcn_sched_barrier(0);
        p2s<4>(B0, B1, B2, B3, wv, a1);                      // jr5
        LD4(icn, y0P + 1, B0, B1, B2, B3)
        __builtin_amdgcn_sched_barrier(0);
      }
      // fire (row y0 then y0+1, xx asc) into registers
      float f0[14], f1[14];
#pragma unroll
      for (int j = 0; j < 7; ++j) {
        {
          int li = ocP * 196 + y0P * 14 + 2 * j;
          float m = m2_l[li] + a0[j].x;
          float sp = 0.f;
          if (m > 1.0f) { sp = 1.f; m = 0.f; }
          m2_l[li] = m;
          f0[2 * j] = sp;
        }
        {
          int li = ocP * 196 + y0P * 14 + 2 * j + 1;
          float m = m2_l[li] + a0[j].y;
          float sp = 0.f;
          if (m > 1.0f) { sp = 1.f; m = 0.f; }
          m2_l[li] = m;
          f0[2 * j + 1] = sp;
        }
      }
#pragma unroll
      for (int j = 0; j < 7; ++j) {
        {
          int li = ocP * 196 + (y0P + 1) * 14 + 2 * j;
          float m = m2_l[li] + a1[j].x;
          float sp = 0.f;
          if (m > 1.0f) { sp = 1.f; m = 0.f; }
          m2_l[li] = m;
          f1[2 * j] = sp;
        }
        {
          int li = ocP * 196 + (y0P + 1) * 14 + 2 * j + 1;
          float m = m2_l[li] + a1[j].y;
          float sp = 0.f;
          if (m > 1.0f) { sp = 1.f; m = 0.f; }
          m2_l[li] = m;
          f1[2 * j + 1] = sp;
        }
      }
      // fused pool2 + fire (thread owns pool row yo = t%7 of ocP)
      uint32_t byte = 0;
#pragma unroll
      for (int xo = 0; xo < 7; ++xo) {
        float a = 0.25f * (((f0[2 * xo] + f0[2 * xo + 1]) + f1[2 * xo]) +
                           f1[2 * xo + 1]);
        int e = ocP * 49 + (t % 7) * 7 + xo;
        float m = m2s_l[e] + a;
        uint32_t bit = 0;
        if (m > 0.75f) { bit = 1; m = 0.f; }
        m2s_l[e] = m;
        byte |= bit << xo;
      }
      fb[t] = (uint8_t)byte;
    } else if (sing2) {
      f2 a0[7];
#pragma unroll
      for (int j = 0; j < 7; ++j) a0[j] = f2{0.f, 0.f};
      float4 A0, A1, A2, A3, B0, B1, B2, B3;
#pragma unroll 1
      for (int ic = 0; ic < 20; ++ic) {
        float wv[28];
        {
          const float4* wb4 =
              reinterpret_cast<const float4*>(wT2 + ocS * 560 + ic * 28);
#pragma unroll
          for (int j = 0; j < 7; ++j) {
            float4 q = wb4[j];
            wv[4 * j]     = q.x;
            wv[4 * j + 1] = q.y;
            wv[4 * j + 2] = q.z;
            wv[4 * j + 3] = q.w;
          }
        }
        LD4(ic, yS + 0, A0, A1, A2, A3)
        LD4(ic, yS + 1, B0, B1, B2, B3)
        p2s<0>(A0, A1, A2, A3, wv, a0);                      // ky0
        LD4(ic, yS + 2, A0, A1, A2, A3)
        __builtin_amdgcn_sched_barrier(0);
        p2s<1>(B0, B1, B2, B3, wv, a0);                      // ky1
        LD4(ic, yS + 3, B0, B1, B2, B3)
        __builtin_amdgcn_sched_barrier(0);
        p2s<2>(A0, A1, A2, A3, wv, a0);                      // ky2
        LD4(ic, yS + 4, A0, A1, A2, A3)
        __builtin_amdgcn_sched_barrier(0);
        p2s<3>(B0, B1, B2, B3, wv, a0);                      // ky3
        __builtin_amdgcn_sched_barrier(0);
        p2s<4>(A0, A1, A2, A3, wv, a0);                      // ky4
        __builtin_amdgcn_sched_barrier(0);
      }
      // fire (row yS, xx asc) into registers + bit pack
      float sf[14];
      uint32_t rb = 0;
#pragma unroll
      for (int j = 0; j < 7; ++j) {
        {
          int li = ocS * 196 + yS * 14 + 2 * j;
          float m = m2_l[li] + a0[j].x;
          float sp = 0.f;
          if (m > 1.0f) { sp = 1.f; m = 0.f; }
          m2_l[li] = m;
          sf[2 * j] = sp;
          rb |= (sp > 0.f ? 1u : 0u) << (2 * j);
        }
        {
          int li = ocS * 196 + yS * 14 + 2 * j + 1;
          float m = m2_l[li] + a0[j].y;
          float sp = 0.f;
          if (m > 1.0f) { sp = 1.f; m = 0.f; }
          m2_l[li] = m;
          sf[2 * j + 1] = sp;
          rb |= (sp > 0.f ? 1u : 0u) << (2 * j + 1);
        }
      }
      // partner row (yS odd) bits via one shfl; even-row threads pool.
      uint32_t pb = (uint32_t)__shfl_down((int)rb, 1);
      if ((yS & 1) == 0) {
        uint32_t byte = 0;
#pragma unroll
        for (int xo = 0; xo < 7; ++xo) {
          float s00 = sf[2 * xo];
          float s01 = sf[2 * xo + 1];
          float s10 = (float)((pb >> (2 * xo)) & 1u);
          float s11 = (float)((pb >> (2 * xo + 1)) & 1u);
          float a = 0.25f * (((s00 + s01) + s10) + s11);
          int e = ocS * 49 + (yS >> 1) * 7 + xo;
          float m = m2s_l[e] + a;
          uint32_t bit = 0;
          if (m > 0.75f) { bit = 1; m = 0.f; }
          m2s_l[e] = m;
          byte |= bit << xo;
        }
        fb[ocS * 7 + (yS >> 1)] = (uint8_t)byte;
      }
    }
    // poisson(s+1) tail of the P2 phase (all threads; ~300 cyc)
    if (s + 1 < STEPS) {
      uint32_t k0 = kb[2 * (s + 1)], k1 = kb[2 * (s + 1) + 1];
      for (int p = t; p < 784; p += 512) {
        uint32_t o0, o1;
        tf2x32(k0, k1, 0u, (uint32_t)(b * 784 + p), o0, o1);
        float r = __uint_as_float(((o0 ^ o1) >> 9) | 0x3F800000u) - 1.0f;
        float v = xhs_l[p];
        pois_l[(p / 28 + 2) * 34 + (p % 28 + 2)] =
            (fabsf(v) > r) ? ((v > 0.f) ? 1.f : -1.f) : 0.f;
      }
    }
    __syncthreads();

    // ---- word assembly: bit e of sp2 stream = fb[e/7] bit (e%7) ----
    if (t < 77) {
      int j0 = (32 * t) / 7;
      uint64_t accw = 0;
#pragma unroll
      for (int jj = 0; jj < 6; ++jj) {
        int j = j0 + jj;
        uint32_t bv = (j < 350) ? (uint32_t)fb[j] : 0u;
        accw |= (uint64_t)bv << (7 * j - 32 * t + 6);
      }
      sp2g[b * 7700 + s * 77 + t] = (uint32_t)(accw >> 6);
    }
    // no barrier: next-P1 reads pois (written pre-barrier); assembly reads
    // fb (pre-barrier); fb next written only after the next barrier. Safe
    // (v18-proven pattern).
  }
#undef LDROW
#undef LD4
}

// ---------------------------------------------------------------------------
// fc0 (R14-proven): block = sample, lane = neuron; wave-uniform ctz over
// spike bits; acc += wf0T[k][n] coalesced; k ascending -> bit-identical.
// ---------------------------------------------------------------------------
__global__ __launch_bounds__(256) void fc0f_k(
    const uint32_t* __restrict__ sp2g, const float* __restrict__ wf0T,
    float* __restrict__ Tf0g) {
  __shared__ uint32_t mk[77];
  const int b = blockIdx.x;
  const int n = threadIdx.x;
  float m = 0.f, T = 0.f;
  for (int s = 0; s < STEPS; ++s) {
    __syncthreads();
    if (n < 77) mk[n] = sp2g[b * 7700 + s * 77 + n];
    __syncthreads();
    float acc = 0.f;
    for (int d = 0; d < 77; ++d) {
      uint32_t um = mk[d];
      while (um) {
        int j = __builtin_ctz(um);
        um &= um - 1;
        acc += wf0T[((d << 5) + j) * 256 + n];
      }
    }
    m += acc;
    if (m > 1.0f) { T += 1.f; m = 0.f; }
  }
  if (n < 200) Tf0g[b * 200 + n] = T;
}

// ---------------------------------------------------------------------------
// final: out[b][i] = (Tf0[b][:] . wf1[i][:]) / 1 / 100   (j ascending)
// ---------------------------------------------------------------------------
__global__ void fc1_k(const float* __restrict__ Tf0,
                      const float* __restrict__ wf1,
                      float* __restrict__ out) {
  int idx = blockIdx.x * blockDim.x + threadIdx.x;
  if (idx >= 5120) return;
  int b = idx / 10, i = idx % 10;
  float a = 0.f;
  for (int j = 0; j < 200; ++j) a += Tf0[b * 200 + j] * wf1[i * 200 + j];
  out[idx] = (a / 1.0f) / 100.0f;
}

// ---------------------------------------------------------------------------
extern "C" void kernel_launch(void* const* d_in, const int* in_sizes, int n_in,
                              void* d_out, int out_size, void* d_ws, size_t ws_size,
                              hipStream_t stream) {
  (void)in_sizes; (void)n_in; (void)out_size; (void)ws_size;
  const float* x   = (const float*)d_in[0];
  const float* w1  = (const float*)d_in[1];
  const float* w2  = (const float*)d_in[2];
  const float* wf0 = (const float*)d_in[3];
  const float* wf1 = (const float*)d_in[4];
  float* out = (float*)d_out;
  char* ws = (char*)d_ws;

  // workspace: Tf0 | wT2 | keys | wf0T | sp2 bitmask  (~18.9 MB)
  const size_t tf0_b  = 512ull * 200 * 4;
  const size_t wt_b   = 50ull * 560 * 4;   // 112000 B
  const size_t key_b  = 1024;
  const size_t wf0t_b = 2450ull * 256 * 4;
  float*    Tf0g = (float*)ws;
  float*    wT2  = (float*)(ws + tf0_b);
  uint32_t* kb   = (uint32_t*)(ws + tf0_b + wt_b);
  float*    wf0T = (float*)(ws + tf0_b + wt_b + key_b);
  uint32_t* sp2g = (uint32_t*)(ws + tf0_b + wt_b + key_b + wf0t_b);

  keys_k<<<1, 128, 0, stream>>>(kb);
  wt_k<<<110, 256, 0, stream>>>(w2, wT2);
  wf0t_k<<<2450, 256, 0, stream>>>(wf0, wf0T);
  step_all_k<<<512, 512, 0, stream>>>(x, w1, wT2, kb, sp2g);
  fc0f_k<<<512, 256, 0, stream>>>(sp2g, wf0T, Tf0g);
  fc1_k<<<20, 256, 0, stream>>>(Tf0g, wf1, out);
}